// Round 1
// baseline (401.186 us; speedup 1.0000x reference)
//
#include <hip/hip_runtime.h>
#include <math.h>

#define BB 64
#define SS 512
#define HH 768
#define AA1 100
#define CC1 300

// ---------------------------------------------------------------------------
// Kernel 1: token attention scores
// token_att[b,s] = sigmoid( tanh(hs[b,s,:] @ w1 + b1) @ w2 + b2 )
// GEMM: M=32768 tokens, N=100, K=768. 64 tokens/block, KT=64.
// Thread tile: 8 tokens x 4 units (200 active threads of 256).
// ---------------------------------------------------------------------------
__global__ __launch_bounds__(256) void k_token_att(
        const float* __restrict__ hs, const float* __restrict__ w1,
        const float* __restrict__ b1, const float* __restrict__ w2,
        const float* __restrict__ b2, float* __restrict__ token_att) {
    __shared__ float hs_lds[64 * 65];    // [token][k], pad 65 to break conflicts
    __shared__ float w1_lds[64 * 100];   // [k][j]
    __shared__ float part[64 * 26];      // [token][jg] partial dot for stage 2

    const int tid = threadIdx.x;
    const int tok0 = blockIdx.x * 64;
    const int tg = tid & 7;      // token group 0..7
    const int jg = tid >> 3;     // unit group 0..31 (active < 25)
    const bool active = (jg < 25);

    float acc[8][4];
#pragma unroll
    for (int i = 0; i < 8; i++)
#pragma unroll
        for (int u = 0; u < 4; u++) acc[i][u] = 0.f;

    for (int ko = 0; ko < HH; ko += 64) {
        // stage hs tile: 64 tokens x 64 k (16 float4 per token)
        for (int i = tid; i < 64 * 16; i += 256) {
            int t = i >> 4, c = i & 15;
            float4 v = *(const float4*)(hs + (size_t)(tok0 + t) * HH + ko + c * 4);
            float* dst = &hs_lds[t * 65 + c * 4];
            dst[0] = v.x; dst[1] = v.y; dst[2] = v.z; dst[3] = v.w;
        }
        // stage w1 tile: rows ko..ko+63 are contiguous in w1 (row-major 768x100)
        for (int i = tid; i < 1600; i += 256) {
            float4 v = *(const float4*)(w1 + ko * 100 + i * 4);
            *(float4*)&w1_lds[i * 4] = v;
        }
        __syncthreads();
        if (active) {
            for (int k = 0; k < 64; k++) {
                float4 wv = *(const float4*)&w1_lds[k * 100 + jg * 4];
#pragma unroll
                for (int i = 0; i < 8; i++) {
                    float a = hs_lds[(tg * 8 + i) * 65 + k];
                    acc[i][0] += a * wv.x;
                    acc[i][1] += a * wv.y;
                    acc[i][2] += a * wv.z;
                    acc[i][3] += a * wv.w;
                }
            }
        }
        __syncthreads();
    }

    // stage 2: tanh + dot with w2 (per-thread partial over its 4 units)
    if (active) {
#pragma unroll
        for (int i = 0; i < 8; i++) {
            float p = 0.f;
#pragma unroll
            for (int u = 0; u < 4; u++) {
                int j = jg * 4 + u;
                float z = tanhf(acc[i][u] + b1[j]);
                p += z * w2[j];
            }
            part[(tg * 8 + i) * 26 + jg] = p;
        }
    }
    __syncthreads();
    if (tid < 64) {
        float sum = 0.f;
#pragma unroll
        for (int j = 0; j < 25; j++) sum += part[tid * 26 + j];
        float att = 1.f / (1.f + expf(-(sum + b2[0])));
        token_att[tok0 + tid] = att;
    }
}

// ---------------------------------------------------------------------------
// Kernel 2: per-row segment ids (scan), segment max, masking, row reductions
// one block (512 threads) per batch row
// ---------------------------------------------------------------------------
__global__ __launch_bounds__(512) void k_row(
        const float* __restrict__ token_att, const float* __restrict__ labels,
        const int* __restrict__ offm, float* __restrict__ masked_out,
        float* __restrict__ att_sum, float* __restrict__ max_masked,
        float* __restrict__ min_ones, float* __restrict__ slabel,
        float* __restrict__ token_loss_b) {
    __shared__ int scan[512];
    __shared__ int smax[512];   // float bits, valid for positive floats
    __shared__ float red[512];

    const int b = blockIdx.x, s = threadIdx.x;
    const int ns = (offm[(b * SS + s) * 2] == 0) ? 1 : 0;

    scan[s] = ns;
    __syncthreads();
    // Hillis-Steele inclusive scan over 512
    for (int off = 1; off < 512; off <<= 1) {
        int v = scan[s];
        int add = (s >= off) ? scan[s - off] : 0;
        __syncthreads();
        scan[s] = v + add;
        __syncthreads();
    }
    const int seg = max(scan[s] - 1, 0);
    const float ta = token_att[b * SS + s];

    smax[s] = 0;
    __syncthreads();
    atomicMax(&smax[seg], __float_as_int(ta));   // sigmoid > 0 -> int order ok
    __syncthreads();

    const float wa = ns ? __int_as_float(smax[seg]) : 0.f;
    const float lab = labels[b * SS + s];
    const float mask = (lab != -1.f && ns) ? 1.f : 0.f;
    const float m = wa * mask;
    masked_out[b * SS + s] = m;

    const float zl = (lab != -1.f) ? lab : 0.f;
    const float tl = (m - zl) * (m - zl);
    const float ones = (m == 0.f) ? 1.f : m;

    // --- reductions ---
    red[s] = m; __syncthreads();
    for (int off = 256; off > 0; off >>= 1) { if (s < off) red[s] += red[s + off]; __syncthreads(); }
    float r_sum = red[0]; __syncthreads();

    red[s] = tl; __syncthreads();
    for (int off = 256; off > 0; off >>= 1) { if (s < off) red[s] += red[s + off]; __syncthreads(); }
    float r_tl = red[0]; __syncthreads();

    red[s] = m; __syncthreads();
    for (int off = 256; off > 0; off >>= 1) { if (s < off) red[s] = fmaxf(red[s], red[s + off]); __syncthreads(); }
    float r_maxm = red[0]; __syncthreads();

    red[s] = ones; __syncthreads();
    for (int off = 256; off > 0; off >>= 1) { if (s < off) red[s] = fminf(red[s], red[s + off]); __syncthreads(); }
    float r_min = red[0]; __syncthreads();

    red[s] = lab; __syncthreads();
    for (int off = 256; off > 0; off >>= 1) { if (s < off) red[s] = fmaxf(red[s], red[s + off]); __syncthreads(); }

    if (s == 0) {
        att_sum[b] = r_sum;
        token_loss_b[b] = r_tl;
        max_masked[b] = r_maxm;
        min_ones[b] = r_min;
        slabel[b] = red[0];
    }
}

// ---------------------------------------------------------------------------
// Kernel 3: pooled[b,h] = sum_s hs[b,s,h] * masked[b,s] / att_sum[b]
// one block (256 threads) per row; skip zero-weight s (uniform branch)
// ---------------------------------------------------------------------------
__global__ __launch_bounds__(256) void k_pool(
        const float* __restrict__ hs, const float* __restrict__ masked,
        const float* __restrict__ att_sum, float* __restrict__ pooled) {
    __shared__ float w[512];
    const int b = blockIdx.x, tid = threadIdx.x;
    const float inv = 1.f / att_sum[b];
    for (int i = tid; i < 512; i += 256) w[i] = masked[b * SS + i] * inv;
    __syncthreads();
    float acc0 = 0.f, acc1 = 0.f, acc2 = 0.f;
    const float* hsb = hs + (size_t)b * SS * HH;
    for (int s = 0; s < SS; s++) {
        float ws_ = w[s];
        if (ws_ != 0.f) {
            acc0 += hsb[(size_t)s * HH + tid] * ws_;
            acc1 += hsb[(size_t)s * HH + tid + 256] * ws_;
            acc2 += hsb[(size_t)s * HH + tid + 512] * ws_;
        }
    }
    pooled[b * HH + tid] = acc0;
    pooled[b * HH + tid + 256] = acc1;
    pooled[b * HH + tid + 512] = acc2;
}

// ---------------------------------------------------------------------------
// Kernel 4: sent[b] = sigmoid( tanh(pooled @ sw1 + sb1) @ sw2 + sb2 )
// one block (256 threads) per row
// ---------------------------------------------------------------------------
__global__ __launch_bounds__(256) void k_sent(
        const float* __restrict__ pooled, const float* __restrict__ sw1,
        const float* __restrict__ sb1, const float* __restrict__ sw2,
        const float* __restrict__ sb2, float* __restrict__ sent) {
    __shared__ float p[768];
    __shared__ float red[256];
    const int b = blockIdx.x, tid = threadIdx.x;
    for (int i = tid; i < HH; i += 256) p[i] = pooled[b * HH + i];
    __syncthreads();
    float partial = 0.f;
    for (int u = tid; u < CC1; u += 256) {
        float z = sb1[u];
        for (int k = 0; k < HH; k++) z += p[k] * sw1[k * CC1 + u];
        partial += tanhf(z) * sw2[u];
    }
    red[tid] = partial; __syncthreads();
    for (int off = 128; off > 0; off >>= 1) { if (tid < off) red[tid] += red[tid + off]; __syncthreads(); }
    if (tid == 0) sent[b] = 1.f / (1.f + expf(-(red[0] + sb2[0])));
}

// ---------------------------------------------------------------------------
// Kernel 5: assemble losses (one wave over B=64)
// ---------------------------------------------------------------------------
__global__ __launch_bounds__(64) void k_final(
        const float* __restrict__ sent, const float* __restrict__ slabel,
        const float* __restrict__ max_masked, const float* __restrict__ min_ones,
        const float* __restrict__ token_loss_b, float* __restrict__ out) {
    const int tid = threadIdx.x;
    float d = sent[tid] - slabel[tid];
    float v_sent = d * d;
    float v_tok = token_loss_b[tid];
    float mo = min_ones[tid];
    float v_ra = mo * mo;
    float rb = max_masked[tid] - slabel[tid];
    float v_rb = rb * rb;
#pragma unroll
    for (int off = 32; off > 0; off >>= 1) {
        v_sent += __shfl_down(v_sent, off);
        v_tok  += __shfl_down(v_tok, off);
        v_ra   += __shfl_down(v_ra, off);
        v_rb   += __shfl_down(v_rb, off);
    }
    if (tid == 0) {
        out[1] = v_sent;
        out[2] = v_tok;
        out[3] = v_ra;
        out[4] = v_rb;
        out[0] = v_sent + v_tok + 0.01f * (v_ra + v_rb);
    }
}

extern "C" void kernel_launch(void* const* d_in, const int* in_sizes, int n_in,
                              void* d_out, int out_size, void* d_ws, size_t ws_size,
                              hipStream_t stream) {
    const float* hs  = (const float*)d_in[0];
    const float* w1  = (const float*)d_in[1];
    const float* b1  = (const float*)d_in[2];
    const float* w2  = (const float*)d_in[3];
    const float* b2  = (const float*)d_in[4];
    const float* sw1 = (const float*)d_in[5];
    const float* sb1 = (const float*)d_in[6];
    const float* sw2 = (const float*)d_in[7];
    const float* sb2 = (const float*)d_in[8];
    const float* labels = (const float*)d_in[9];
    const int*   offm   = (const int*)d_in[10];

    float* out = (float*)d_out;
    float* ws  = (float*)d_ws;

    // ws layout (floats)
    float* token_att    = ws;                    // 32768
    float* pooled       = ws + 32768;            // 49152
    float* att_sum      = ws + 32768 + 49152;    // 64
    float* max_masked   = att_sum + 64;
    float* min_ones     = max_masked + 64;
    float* slabel       = min_ones + 64;
    float* token_loss_b = slabel + 64;

    // d_out layout: [total, sentence_loss, token_loss, reg_a, reg_b,
    //                masked(64*512), sent(64)]
    float* masked_out = out + 5;
    float* sent       = out + 5 + BB * SS;

    hipLaunchKernelGGL(k_token_att, dim3(512), dim3(256), 0, stream,
                       hs, w1, b1, w2, b2, token_att);
    hipLaunchKernelGGL(k_row, dim3(BB), dim3(512), 0, stream,
                       token_att, labels, offm, masked_out,
                       att_sum, max_masked, min_ones, slabel, token_loss_b);
    hipLaunchKernelGGL(k_pool, dim3(BB), dim3(256), 0, stream,
                       hs, masked_out, att_sum, pooled);
    hipLaunchKernelGGL(k_sent, dim3(BB), dim3(256), 0, stream,
                       pooled, sw1, sb1, sw2, sb2, sent);
    hipLaunchKernelGGL(k_final, dim3(1), dim3(64), 0, stream,
                       sent, slabel, max_masked, min_ones, token_loss_b, out);
}

// Round 2
// 274.179 us; speedup vs baseline: 1.4632x; 1.4632x over previous
//
#include <hip/hip_runtime.h>
#include <math.h>

#define BB 64
#define SS 512
#define HH 768
#define AA1 100
#define CC1 300
#define NPAD 112

typedef __bf16 bf16x8 __attribute__((ext_vector_type(8)));
typedef __bf16 bf16x4 __attribute__((ext_vector_type(4)));
typedef float f32x4 __attribute__((ext_vector_type(4)));

// ---------------------------------------------------------------------------
// Prep: w1t[j][k] = bf16(w1[k][j]) for j<100, 0 for j in [100,112)
// ---------------------------------------------------------------------------
__global__ __launch_bounds__(256) void k_prep(const float* __restrict__ w1,
                                              __bf16* __restrict__ w1t) {
    int idx = blockIdx.x * 256 + threadIdx.x;   // 112*768 = 86016 = 336*256
    int j = idx / HH, k = idx - j * HH;
    float v = (j < AA1) ? w1[k * AA1 + j] : 0.f;
    w1t[idx] = (__bf16)v;
}

// ---------------------------------------------------------------------------
// Kernel 1: token attention via bf16 MFMA 16x16x32.
// 64 tokens/block, N padded to 112 (7 tiles), K-loop 24 x 32.
// wave w handles tokens w*16..w*16+15, all 7 N-tiles (acc = 7 x f32x4).
// LDS rows padded to 40 bf16 (80B): frag b128 reads are 2-way (free).
// ---------------------------------------------------------------------------
__global__ __launch_bounds__(256) void k_token_att(
        const float* __restrict__ hs, const __bf16* __restrict__ w1t,
        const float* __restrict__ b1, const float* __restrict__ w2,
        const float* __restrict__ b2, float* __restrict__ token_att) {
    __shared__ __bf16 lA[64 * 40];     // [token][k] stride 40
    __shared__ __bf16 lB[NPAD * 40];   // [unit][k] stride 40

    const int tid = threadIdx.x;
    const int tok0 = blockIdx.x * 64;
    const int w = tid >> 6, lane = tid & 63;
    const int q = lane >> 4, ln = lane & 15;

    f32x4 acc[7];
#pragma unroll
    for (int n = 0; n < 7; n++) acc[n] = (f32x4){0.f, 0.f, 0.f, 0.f};

    for (int ko = 0; ko < HH; ko += 32) {
        // stage A: 64 rows x 32 k fp32 -> bf16 (512 float4 loads, 2/thread)
#pragma unroll
        for (int it = 0; it < 2; it++) {
            int i = tid + it * 256;
            int t = i >> 3, c = i & 7;
            float4 v = *(const float4*)(hs + (size_t)(tok0 + t) * HH + ko + c * 4);
            bf16x4 pk = { (__bf16)v.x, (__bf16)v.y, (__bf16)v.z, (__bf16)v.w };
            *(bf16x4*)&lA[t * 40 + c * 4] = pk;
        }
        // stage B: 112 rows x 32 k bf16 (448 x 16B, <2/thread)
        {
            int j = tid >> 2, c = tid & 3;
            *(bf16x8*)&lB[j * 40 + c * 8] = *(const bf16x8*)(w1t + j * HH + ko + c * 8);
            int i = tid + 256;
            if (i < 448) {
                j = i >> 2; c = i & 3;
                *(bf16x8*)&lB[j * 40 + c * 8] = *(const bf16x8*)(w1t + j * HH + ko + c * 8);
            }
        }
        __syncthreads();
        bf16x8 af = *(bf16x8*)&lA[(w * 16 + ln) * 40 + q * 8];
#pragma unroll
        for (int n = 0; n < 7; n++) {
            bf16x8 bf = *(bf16x8*)&lB[(n * 16 + ln) * 40 + q * 8];
            acc[n] = __builtin_amdgcn_mfma_f32_16x16x32_bf16(af, bf, acc[n], 0, 0, 0);
        }
        __syncthreads();
    }

    // epilogue: C/D layout col=lane&15 (unit j), row=quad*4+reg (token)
    float p0 = 0.f, p1 = 0.f, p2 = 0.f, p3 = 0.f;
#pragma unroll
    for (int n = 0; n < 7; n++) {
        int j = n * 16 + ln;
        if (j < AA1) {
            float bj = b1[j], wj = w2[j];
            p0 += tanhf(acc[n][0] + bj) * wj;
            p1 += tanhf(acc[n][1] + bj) * wj;
            p2 += tanhf(acc[n][2] + bj) * wj;
            p3 += tanhf(acc[n][3] + bj) * wj;
        }
    }
#pragma unroll
    for (int off = 1; off < 16; off <<= 1) {
        p0 += __shfl_xor(p0, off);
        p1 += __shfl_xor(p1, off);
        p2 += __shfl_xor(p2, off);
        p3 += __shfl_xor(p3, off);
    }
    if (ln == 0) {
        float bb = b2[0];
        int base = tok0 + w * 16 + q * 4;
        token_att[base + 0] = 1.f / (1.f + expf(-(p0 + bb)));
        token_att[base + 1] = 1.f / (1.f + expf(-(p1 + bb)));
        token_att[base + 2] = 1.f / (1.f + expf(-(p2 + bb)));
        token_att[base + 3] = 1.f / (1.f + expf(-(p3 + bb)));
    }
}

// ---------------------------------------------------------------------------
// Kernel 2: per-row scan/segmax/mask + 5 reductions, shuffle-based (2 barriers)
// ---------------------------------------------------------------------------
__global__ __launch_bounds__(512) void k_row(
        const float* __restrict__ token_att, const float* __restrict__ labels,
        const int* __restrict__ offm, float* __restrict__ masked_out,
        float* __restrict__ att_sum, float* __restrict__ max_masked,
        float* __restrict__ min_ones, float* __restrict__ slabel,
        float* __restrict__ token_loss_b) {
    __shared__ int smax[512];
    __shared__ int wscan[8];
    __shared__ float wred[5][8];

    const int b = blockIdx.x, s = threadIdx.x;
    const int lane = s & 63, wv = s >> 6;
    const int ns = (offm[(b * SS + s) * 2] == 0) ? 1 : 0;

    // wave-level inclusive scan
    int v = ns;
#pragma unroll
    for (int off = 1; off < 64; off <<= 1) {
        int o = __shfl_up(v, off);
        if (lane >= off) v += o;
    }
    if (lane == 63) wscan[wv] = v;
    smax[s] = 0;
    __syncthreads();
    int woff = 0;
    for (int i = 0; i < 8; i++) woff += (i < wv) ? wscan[i] : 0;
    const int seg = max(v + woff - 1, 0);

    const float ta = token_att[b * SS + s];
    atomicMax(&smax[seg], __float_as_int(ta));   // sigmoid > 0: int order ok
    __syncthreads();

    const float wa = ns ? __int_as_float(smax[seg]) : 0.f;
    const float lab = labels[b * SS + s];
    const float m = (lab != -1.f && ns) ? wa : 0.f;
    masked_out[b * SS + s] = m;

    const float zl = (lab != -1.f) ? lab : 0.f;
    const float tl = (m - zl) * (m - zl);
    const float ones = (m == 0.f) ? 1.f : m;

    float r0 = m, r1 = tl, r2 = m, r3 = ones, r4 = lab;
#pragma unroll
    for (int off = 32; off > 0; off >>= 1) {
        r0 += __shfl_xor(r0, off);
        r1 += __shfl_xor(r1, off);
        r2 = fmaxf(r2, __shfl_xor(r2, off));
        r3 = fminf(r3, __shfl_xor(r3, off));
        r4 = fmaxf(r4, __shfl_xor(r4, off));
    }
    if (lane == 0) {
        wred[0][wv] = r0; wred[1][wv] = r1; wred[2][wv] = r2;
        wred[3][wv] = r3; wred[4][wv] = r4;
    }
    __syncthreads();
    if (s == 0) {
        float a0 = wred[0][0], a1 = wred[1][0], a2 = wred[2][0];
        float a3 = wred[3][0], a4 = wred[4][0];
        for (int i = 1; i < 8; i++) {
            a0 += wred[0][i]; a1 += wred[1][i];
            a2 = fmaxf(a2, wred[2][i]);
            a3 = fminf(a3, wred[3][i]);
            a4 = fmaxf(a4, wred[4][i]);
        }
        att_sum[b] = a0; token_loss_b[b] = a1; max_masked[b] = a2;
        min_ones[b] = a3; slabel[b] = a4;
    }
}

// ---------------------------------------------------------------------------
// Kernel 3: pooled[b,h] += sum_s hs[b,s,h]*masked[b,s], s split 4 ways
// (normalization by att_sum deferred to k_sent; pooled pre-zeroed)
// ---------------------------------------------------------------------------
__global__ __launch_bounds__(256) void k_pool(
        const float* __restrict__ hs, const float* __restrict__ masked,
        float* __restrict__ pooled) {
    const int b = blockIdx.x, ch = blockIdx.y, tid = threadIdx.x;
    __shared__ float w[128];
    if (tid < 128) w[tid] = masked[b * SS + ch * 128 + tid];
    __syncthreads();
    float a0 = 0.f, a1 = 0.f, a2 = 0.f;
    const float* hsb = hs + (size_t)b * SS * HH + (size_t)ch * 128 * HH;
    for (int s = 0; s < 128; s++) {
        float ws_ = w[s];
        if (ws_ != 0.f) {
            a0 += hsb[(size_t)s * HH + tid] * ws_;
            a1 += hsb[(size_t)s * HH + tid + 256] * ws_;
            a2 += hsb[(size_t)s * HH + tid + 512] * ws_;
        }
    }
    atomicAdd(&pooled[b * HH + tid], a0);
    atomicAdd(&pooled[b * HH + tid + 256], a1);
    atomicAdd(&pooled[b * HH + tid + 512], a2);
}

// ---------------------------------------------------------------------------
// Kernel 4: sentence MLP
// ---------------------------------------------------------------------------
__global__ __launch_bounds__(256) void k_sent(
        const float* __restrict__ pooled, const float* __restrict__ att_sum,
        const float* __restrict__ sw1, const float* __restrict__ sb1,
        const float* __restrict__ sw2, const float* __restrict__ sb2,
        float* __restrict__ sent) {
    __shared__ float p[HH];
    __shared__ float red[256];
    const int b = blockIdx.x, tid = threadIdx.x;
    const float inv = 1.f / att_sum[b];
    for (int i = tid; i < HH; i += 256) p[i] = pooled[b * HH + i] * inv;
    __syncthreads();
    float partial = 0.f;
    for (int u = tid; u < CC1; u += 256) {
        float z = sb1[u];
        for (int k = 0; k < HH; k++) z += p[k] * sw1[k * CC1 + u];
        partial += tanhf(z) * sw2[u];
    }
    red[tid] = partial; __syncthreads();
    for (int off = 128; off > 0; off >>= 1) {
        if (tid < off) red[tid] += red[tid + off];
        __syncthreads();
    }
    if (tid == 0) sent[b] = 1.f / (1.f + expf(-(red[0] + sb2[0])));
}

// ---------------------------------------------------------------------------
// Kernel 5: assemble losses
// ---------------------------------------------------------------------------
__global__ __launch_bounds__(64) void k_final(
        const float* __restrict__ sent, const float* __restrict__ slabel,
        const float* __restrict__ max_masked, const float* __restrict__ min_ones,
        const float* __restrict__ token_loss_b, float* __restrict__ out) {
    const int tid = threadIdx.x;
    float d = sent[tid] - slabel[tid];
    float v_sent = d * d;
    float v_tok = token_loss_b[tid];
    float mo = min_ones[tid];
    float v_ra = mo * mo;
    float rb = max_masked[tid] - slabel[tid];
    float v_rb = rb * rb;
#pragma unroll
    for (int off = 32; off > 0; off >>= 1) {
        v_sent += __shfl_down(v_sent, off);
        v_tok  += __shfl_down(v_tok, off);
        v_ra   += __shfl_down(v_ra, off);
        v_rb   += __shfl_down(v_rb, off);
    }
    if (tid == 0) {
        out[1] = v_sent;
        out[2] = v_tok;
        out[3] = v_ra;
        out[4] = v_rb;
        out[0] = v_sent + v_tok + 0.01f * (v_ra + v_rb);
    }
}

extern "C" void kernel_launch(void* const* d_in, const int* in_sizes, int n_in,
                              void* d_out, int out_size, void* d_ws, size_t ws_size,
                              hipStream_t stream) {
    const float* hs  = (const float*)d_in[0];
    const float* w1  = (const float*)d_in[1];
    const float* b1  = (const float*)d_in[2];
    const float* w2  = (const float*)d_in[3];
    const float* b2  = (const float*)d_in[4];
    const float* sw1 = (const float*)d_in[5];
    const float* sb1 = (const float*)d_in[6];
    const float* sw2 = (const float*)d_in[7];
    const float* sb2 = (const float*)d_in[8];
    const float* labels = (const float*)d_in[9];
    const int*   offm   = (const int*)d_in[10];

    float* out = (float*)d_out;
    float* ws  = (float*)d_ws;

    // ws layout (float units)
    float*  token_att = ws;                          // 32768
    __bf16* w1t       = (__bf16*)(ws + 32768);       // 86016 bf16 = 43008 f
    float*  pooled    = ws + 32768 + 43008;          // 49152
    float*  att_sum   = pooled + 49152;              // 64 x 5
    float*  max_masked   = att_sum + 64;
    float*  min_ones     = max_masked + 64;
    float*  slabel       = min_ones + 64;
    float*  token_loss_b = slabel + 64;

    float* masked_out = out + 5;
    float* sent       = out + 5 + BB * SS;

    hipMemsetAsync(pooled, 0, 49152 * sizeof(float), stream);
    hipLaunchKernelGGL(k_prep, dim3(336), dim3(256), 0, stream, w1, w1t);
    hipLaunchKernelGGL(k_token_att, dim3(512), dim3(256), 0, stream,
                       hs, w1t, b1, w2, b2, token_att);
    hipLaunchKernelGGL(k_row, dim3(BB), dim3(512), 0, stream,
                       token_att, labels, offm, masked_out,
                       att_sum, max_masked, min_ones, slabel, token_loss_b);
    hipLaunchKernelGGL(k_pool, dim3(BB, 4), dim3(256), 0, stream,
                       hs, masked_out, pooled);
    hipLaunchKernelGGL(k_sent, dim3(BB), dim3(256), 0, stream,
                       pooled, att_sum, sw1, sb1, sw2, sb2, sent);
    hipLaunchKernelGGL(k_final, dim3(1), dim3(64), 0, stream,
                       sent, slabel, max_masked, min_ones, token_loss_b, out);
}

// Round 3
// 248.057 us; speedup vs baseline: 1.6173x; 1.1053x over previous
//
#include <hip/hip_runtime.h>
#include <math.h>

#define BB 64
#define SS 512
#define HH 768
#define AA1 100
#define CC1 300
#define NPAD 112

typedef __bf16 bf16x8 __attribute__((ext_vector_type(8)));
typedef __bf16 bf16x4 __attribute__((ext_vector_type(4)));
typedef float f32x4 __attribute__((ext_vector_type(4)));

// ---------------------------------------------------------------------------
// Prep: w1t[j][k] = bf16(w1[k][j]) for j<100, 0 for j in [100,112)
// ---------------------------------------------------------------------------
__global__ __launch_bounds__(256) void k_prep(const float* __restrict__ w1,
                                              __bf16* __restrict__ w1t) {
    int idx = blockIdx.x * 256 + threadIdx.x;   // 112*768 = 86016 = 336*256
    int j = idx / HH, k = idx - j * HH;
    float v = (j < AA1) ? w1[k * AA1 + j] : 0.f;
    w1t[idx] = (__bf16)v;
}

// ---------------------------------------------------------------------------
// Kernel 1: token attention via bf16 MFMA 16x16x32.
// 64 tokens/block, N padded to 112 (7 tiles), K-loop 24 x 32.
// ---------------------------------------------------------------------------
__global__ __launch_bounds__(256) void k_token_att(
        const float* __restrict__ hs, const __bf16* __restrict__ w1t,
        const float* __restrict__ b1, const float* __restrict__ w2,
        const float* __restrict__ b2, float* __restrict__ token_att) {
    __shared__ __bf16 lA[64 * 40];     // [token][k] stride 40
    __shared__ __bf16 lB[NPAD * 40];   // [unit][k] stride 40

    const int tid = threadIdx.x;
    const int tok0 = blockIdx.x * 64;
    const int w = tid >> 6, lane = tid & 63;
    const int q = lane >> 4, ln = lane & 15;

    f32x4 acc[7];
#pragma unroll
    for (int n = 0; n < 7; n++) acc[n] = (f32x4){0.f, 0.f, 0.f, 0.f};

    for (int ko = 0; ko < HH; ko += 32) {
#pragma unroll
        for (int it = 0; it < 2; it++) {
            int i = tid + it * 256;
            int t = i >> 3, c = i & 7;
            float4 v = *(const float4*)(hs + (size_t)(tok0 + t) * HH + ko + c * 4);
            bf16x4 pk = { (__bf16)v.x, (__bf16)v.y, (__bf16)v.z, (__bf16)v.w };
            *(bf16x4*)&lA[t * 40 + c * 4] = pk;
        }
        {
            int j = tid >> 2, c = tid & 3;
            *(bf16x8*)&lB[j * 40 + c * 8] = *(const bf16x8*)(w1t + j * HH + ko + c * 8);
            int i = tid + 256;
            if (i < 448) {
                j = i >> 2; c = i & 3;
                *(bf16x8*)&lB[j * 40 + c * 8] = *(const bf16x8*)(w1t + j * HH + ko + c * 8);
            }
        }
        __syncthreads();
        bf16x8 af = *(bf16x8*)&lA[(w * 16 + ln) * 40 + q * 8];
#pragma unroll
        for (int n = 0; n < 7; n++) {
            bf16x8 bf = *(bf16x8*)&lB[(n * 16 + ln) * 40 + q * 8];
            acc[n] = __builtin_amdgcn_mfma_f32_16x16x32_bf16(af, bf, acc[n], 0, 0, 0);
        }
        __syncthreads();
    }

    // epilogue: C/D layout col=lane&15 (unit j), row=quad*4+reg (token)
    float p0 = 0.f, p1 = 0.f, p2 = 0.f, p3 = 0.f;
#pragma unroll
    for (int n = 0; n < 7; n++) {
        int j = n * 16 + ln;
        if (j < AA1) {
            float bj = b1[j], wj = w2[j];
            p0 += tanhf(acc[n][0] + bj) * wj;
            p1 += tanhf(acc[n][1] + bj) * wj;
            p2 += tanhf(acc[n][2] + bj) * wj;
            p3 += tanhf(acc[n][3] + bj) * wj;
        }
    }
#pragma unroll
    for (int off = 1; off < 16; off <<= 1) {
        p0 += __shfl_xor(p0, off);
        p1 += __shfl_xor(p1, off);
        p2 += __shfl_xor(p2, off);
        p3 += __shfl_xor(p3, off);
    }
    if (ln == 0) {
        float bb = b2[0];
        int base = tok0 + w * 16 + q * 4;
        token_att[base + 0] = 1.f / (1.f + expf(-(p0 + bb)));
        token_att[base + 1] = 1.f / (1.f + expf(-(p1 + bb)));
        token_att[base + 2] = 1.f / (1.f + expf(-(p2 + bb)));
        token_att[base + 3] = 1.f / (1.f + expf(-(p3 + bb)));
    }
}

// ---------------------------------------------------------------------------
// Kernel 2: per-row scan/segmax/mask + 5 reductions, shuffle-based
// ---------------------------------------------------------------------------
__global__ __launch_bounds__(512) void k_row(
        const float* __restrict__ token_att, const float* __restrict__ labels,
        const int* __restrict__ offm, float* __restrict__ masked_out,
        float* __restrict__ att_sum, float* __restrict__ max_masked,
        float* __restrict__ min_ones, float* __restrict__ slabel,
        float* __restrict__ token_loss_b) {
    __shared__ int smax[512];
    __shared__ int wscan[8];
    __shared__ float wred[5][8];

    const int b = blockIdx.x, s = threadIdx.x;
    const int lane = s & 63, wv = s >> 6;
    const int ns = (offm[(b * SS + s) * 2] == 0) ? 1 : 0;

    int v = ns;
#pragma unroll
    for (int off = 1; off < 64; off <<= 1) {
        int o = __shfl_up(v, off);
        if (lane >= off) v += o;
    }
    if (lane == 63) wscan[wv] = v;
    smax[s] = 0;
    __syncthreads();
    int woff = 0;
    for (int i = 0; i < 8; i++) woff += (i < wv) ? wscan[i] : 0;
    const int seg = max(v + woff - 1, 0);

    const float ta = token_att[b * SS + s];
    atomicMax(&smax[seg], __float_as_int(ta));   // sigmoid > 0: int order ok
    __syncthreads();

    const float wa = ns ? __int_as_float(smax[seg]) : 0.f;
    const float lab = labels[b * SS + s];
    const float m = (lab != -1.f && ns) ? wa : 0.f;
    masked_out[b * SS + s] = m;

    const float zl = (lab != -1.f) ? lab : 0.f;
    const float tl = (m - zl) * (m - zl);
    const float ones = (m == 0.f) ? 1.f : m;

    float r0 = m, r1 = tl, r2 = m, r3 = ones, r4 = lab;
#pragma unroll
    for (int off = 32; off > 0; off >>= 1) {
        r0 += __shfl_xor(r0, off);
        r1 += __shfl_xor(r1, off);
        r2 = fmaxf(r2, __shfl_xor(r2, off));
        r3 = fminf(r3, __shfl_xor(r3, off));
        r4 = fmaxf(r4, __shfl_xor(r4, off));
    }
    if (lane == 0) {
        wred[0][wv] = r0; wred[1][wv] = r1; wred[2][wv] = r2;
        wred[3][wv] = r3; wred[4][wv] = r4;
    }
    __syncthreads();
    if (s == 0) {
        float a0 = wred[0][0], a1 = wred[1][0], a2 = wred[2][0];
        float a3 = wred[3][0], a4 = wred[4][0];
        for (int i = 1; i < 8; i++) {
            a0 += wred[0][i]; a1 += wred[1][i];
            a2 = fmaxf(a2, wred[2][i]);
            a3 = fminf(a3, wred[3][i]);
            a4 = fmaxf(a4, wred[4][i]);
        }
        att_sum[b] = a0; token_loss_b[b] = a1; max_masked[b] = a2;
        min_ones[b] = a3; slabel[b] = a4;
    }
}

// ---------------------------------------------------------------------------
// Kernel 3: pooled[b,h] += sum_s hs[b,s,h]*masked[b,s], s split 8 ways
// ---------------------------------------------------------------------------
__global__ __launch_bounds__(256) void k_pool(
        const float* __restrict__ hs, const float* __restrict__ masked,
        float* __restrict__ pooled) {
    const int b = blockIdx.x, ch = blockIdx.y, tid = threadIdx.x;
    __shared__ float w[64];
    if (tid < 64) w[tid] = masked[b * SS + ch * 64 + tid];
    __syncthreads();
    float a0 = 0.f, a1 = 0.f, a2 = 0.f;
    const float* hsb = hs + (size_t)b * SS * HH + (size_t)ch * 64 * HH;
    for (int s = 0; s < 64; s++) {
        float ws_ = w[s];
        if (ws_ != 0.f) {
            a0 += hsb[(size_t)s * HH + tid] * ws_;
            a1 += hsb[(size_t)s * HH + tid + 256] * ws_;
            a2 += hsb[(size_t)s * HH + tid + 512] * ws_;
        }
    }
    atomicAdd(&pooled[b * HH + tid], a0);
    atomicAdd(&pooled[b * HH + tid + 256], a1);
    atomicAdd(&pooled[b * HH + tid + 512], a2);
}

// ---------------------------------------------------------------------------
// Kernel 4: sentence MLP. One block per batch row, thread = hidden unit.
// u-loop coalesced over sw1 rows; p[k] broadcast from LDS.
// ---------------------------------------------------------------------------
__global__ __launch_bounds__(320) void k_sent(
        const float* __restrict__ pooled, const float* __restrict__ att_sum,
        const float* __restrict__ sw1, const float* __restrict__ sb1,
        const float* __restrict__ sw2, const float* __restrict__ sb2,
        float* __restrict__ sent) {
    __shared__ float p[HH];
    __shared__ float wred[5];
    const int b = blockIdx.x, tid = threadIdx.x;
    const int lane = tid & 63, wv = tid >> 6;
    const float inv = 1.f / att_sum[b];
    for (int i = tid; i < HH; i += 320) p[i] = pooled[b * HH + i] * inv;
    __syncthreads();

    float t = 0.f;
    if (tid < CC1) {
        float z = sb1[tid];
#pragma unroll 8
        for (int k = 0; k < HH; k++) z += p[k] * sw1[k * CC1 + tid];
        t = tanhf(z) * sw2[tid];
    }
#pragma unroll
    for (int off = 32; off > 0; off >>= 1) t += __shfl_xor(t, off);
    if (lane == 0) wred[wv] = t;
    __syncthreads();
    if (tid == 0) {
        float sum = wred[0] + wred[1] + wred[2] + wred[3] + wred[4];
        sent[b] = 1.f / (1.f + expf(-(sum + sb2[0])));
    }
}

// ---------------------------------------------------------------------------
// Kernel 5: assemble losses
// ---------------------------------------------------------------------------
__global__ __launch_bounds__(64) void k_final(
        const float* __restrict__ sent, const float* __restrict__ slabel,
        const float* __restrict__ max_masked, const float* __restrict__ min_ones,
        const float* __restrict__ token_loss_b, float* __restrict__ out) {
    const int tid = threadIdx.x;
    float d = sent[tid] - slabel[tid];
    float v_sent = d * d;
    float v_tok = token_loss_b[tid];
    float mo = min_ones[tid];
    float v_ra = mo * mo;
    float rb = max_masked[tid] - slabel[tid];
    float v_rb = rb * rb;
#pragma unroll
    for (int off = 32; off > 0; off >>= 1) {
        v_sent += __shfl_down(v_sent, off);
        v_tok  += __shfl_down(v_tok, off);
        v_ra   += __shfl_down(v_ra, off);
        v_rb   += __shfl_down(v_rb, off);
    }
    if (tid == 0) {
        out[1] = v_sent;
        out[2] = v_tok;
        out[3] = v_ra;
        out[4] = v_rb;
        out[0] = v_sent + v_tok + 0.01f * (v_ra + v_rb);
    }
}

extern "C" void kernel_launch(void* const* d_in, const int* in_sizes, int n_in,
                              void* d_out, int out_size, void* d_ws, size_t ws_size,
                              hipStream_t stream) {
    const float* hs  = (const float*)d_in[0];
    const float* w1  = (const float*)d_in[1];
    const float* b1  = (const float*)d_in[2];
    const float* w2  = (const float*)d_in[3];
    const float* b2  = (const float*)d_in[4];
    const float* sw1 = (const float*)d_in[5];
    const float* sb1 = (const float*)d_in[6];
    const float* sw2 = (const float*)d_in[7];
    const float* sb2 = (const float*)d_in[8];
    const float* labels = (const float*)d_in[9];
    const int*   offm   = (const int*)d_in[10];

    float* out = (float*)d_out;
    float* ws  = (float*)d_ws;

    // ws layout (float units)
    float*  token_att = ws;                          // 32768
    __bf16* w1t       = (__bf16*)(ws + 32768);       // 86016 bf16 = 43008 f
    float*  pooled    = ws + 32768 + 43008;          // 49152
    float*  att_sum   = pooled + 49152;
    float*  max_masked   = att_sum + 64;
    float*  min_ones     = max_masked + 64;
    float*  slabel       = min_ones + 64;
    float*  token_loss_b = slabel + 64;

    float* masked_out = out + 5;
    float* sent       = out + 5 + BB * SS;

    hipMemsetAsync(pooled, 0, 49152 * sizeof(float), stream);
    hipLaunchKernelGGL(k_prep, dim3(336), dim3(256), 0, stream, w1, w1t);
    hipLaunchKernelGGL(k_token_att, dim3(512), dim3(256), 0, stream,
                       hs, w1t, b1, w2, b2, token_att);
    hipLaunchKernelGGL(k_row, dim3(BB), dim3(512), 0, stream,
                       token_att, labels, offm, masked_out,
                       att_sum, max_masked, min_ones, slabel, token_loss_b);
    hipLaunchKernelGGL(k_pool, dim3(BB, 8), dim3(256), 0, stream,
                       hs, masked_out, pooled);
    hipLaunchKernelGGL(k_sent, dim3(BB), dim3(320), 0, stream,
                       pooled, att_sum, sw1, sb1, sw2, sb2, sent);
    hipLaunchKernelGGL(k_final, dim3(1), dim3(64), 0, stream,
                       sent, slabel, max_masked, min_ones, token_loss_b, out);
}